// Round 1
// baseline (10686.180 us; speedup 1.0000x reference)
//
#include <hip/hip_runtime.h>
#include <stdint.h>

// ComplexModel: 2-layer RNN(tanh) + 2-layer LSTM + FC on MI355X (gfx950)
// B=64 T=1024 D=256 H=256 HL=256 L=2 C=128
#define T_ 1024

typedef short bf16x8 __attribute__((ext_vector_type(8)));
typedef float f32x4  __attribute__((ext_vector_type(4)));
typedef unsigned short u16;

#define MFMA(a,b,c) __builtin_amdgcn_mfma_f32_16x16x32_bf16((a),(b),(c),0,0,0)

__device__ __forceinline__ u16 f2bf(float f){
  unsigned u = __float_as_uint(f);
  return (u16)((u + 0x7FFFu + ((u>>16)&1u)) >> 16);   // RNE
}
__device__ __forceinline__ float bf2f(u16 s){ return __uint_as_float(((unsigned)s)<<16); }
__device__ __forceinline__ float sigm(float x){ return 1.f/(1.f+__expf(-x)); }
__device__ __forceinline__ float tanhq(float x){ return 2.f/(1.f+__expf(-2.f*x)) - 1.f; }

__device__ __forceinline__ void gload16(const void* g, void* l){
  __builtin_amdgcn_global_load_lds(
      (const __attribute__((address_space(1))) unsigned int*)g,
      (__attribute__((address_space(3)))       unsigned int*)l, 16, 0, 0);
}
// raw barrier with LDS-only drain (keeps HBM prefetch in flight across barriers)
__device__ __forceinline__ void lgkm0_barrier(){
  asm volatile("s_waitcnt lgkmcnt(0)" ::: "memory");
  __builtin_amdgcn_s_barrier();
  asm volatile("" ::: "memory");
}

// ---------------- f32 -> bf16 conversion ----------------
__global__ void k_cvt(const float* __restrict__ s, u16* __restrict__ d, int n4){
  int i = blockIdx.x*blockDim.x + threadIdx.x;
  int stride = gridDim.x*blockDim.x;
  for (; i < n4; i += stride){
    float4 v = ((const float4*)s)[i];
    ushort4 o; o.x=f2bf(v.x); o.y=f2bf(v.y); o.z=f2bf(v.z); o.w=f2bf(v.w);
    ((ushort4*)d)[i] = o;
  }
}

// ---------------- bf16 GEMM: C[M,N] = A[M,256] @ B[N,256]^T ----------------
// 128x128 tile, BK=64, 4 waves (2x2 of 64x64), global_load_lds staging.
__global__ __launch_bounds__(256,2) void k_gemm(
    const u16* __restrict__ A, const u16* __restrict__ Bm,
    u16* __restrict__ C, int N)
{
  __shared__ u16 As[128*64];
  __shared__ u16 Bs[128*64];
  const int tid = threadIdx.x;
  const int lane = tid & 63, w = tid >> 6;
  const int l15 = lane & 15, l4 = lane >> 4;
  const long m0 = (long)blockIdx.x * 128;
  const int  n0 = blockIdx.y * 128;
  const int  mo = (w>>1)*64, no = (w&1)*64;

  f32x4 acc[4][4];
  #pragma unroll
  for (int i=0;i<4;++i)
    #pragma unroll
    for (int j=0;j<4;++j) acc[i][j] = (f32x4){0.f,0.f,0.f,0.f};

  for (int kt=0; kt<4; ++kt){
    const int k0 = kt*64;
    #pragma unroll
    for (int i=0;i<4;++i){
      int fb = (i*256+tid)*16;          // byte offset in 16KB tile
      int r  = fb>>7, cbyte = fb&127;   // tile row, byte within 128B row
      gload16(A + (m0 + r)*256 + k0 + (cbyte>>1), (char*)As + fb);
      gload16(Bm + (long)(n0 + r)*256 + k0 + (cbyte>>1), (char*)Bs + fb);
    }
    __syncthreads();
    #pragma unroll
    for (int kb=0;kb<2;++kb){
      bf16x8 a[4], b[4];
      #pragma unroll
      for (int mb=0;mb<4;++mb)
        a[mb] = *(const bf16x8*)(As + (mo+mb*16+l15)*64 + kb*32 + l4*8);
      #pragma unroll
      for (int nb=0;nb<4;++nb)
        b[nb] = *(const bf16x8*)(Bs + (no+nb*16+l15)*64 + kb*32 + l4*8);
      #pragma unroll
      for (int mb=0;mb<4;++mb)
        #pragma unroll
        for (int nb=0;nb<4;++nb)
          acc[mb][nb] = MFMA(a[mb], b[nb], acc[mb][nb]);
    }
    __syncthreads();
  }
  #pragma unroll
  for (int mb=0;mb<4;++mb)
    #pragma unroll
    for (int nb=0;nb<4;++nb)
      #pragma unroll
      for (int j=0;j<4;++j){
        long row = m0 + mo + mb*16 + l4*4 + j;
        int  col = n0 + no + nb*16 + l15;
        C[row*N + col] = f2bf(acc[mb][nb][j]);
      }
}

// ---------------- fused recurrence kernel ----------------
// blocks 0..3 : RNN, batch-split (16 rows each), Whh(hi/lo) in regs, h in LDS.
// blocks 4..19: LSTM, 4 batch-groups x 4 hidden-slices, Whh slice(hi/lo) in regs,
//               h exchanged through global hbuf with per-group flag sync.
__global__ __launch_bounds__(512,2) void k_rec(
    const u16*  __restrict__ projR,  // [B*T][256] bf16
    const float* __restrict__ WhhR,  // [256][256]
    const float* __restrict__ bihR, const float* __restrict__ bhhR,
    u16* __restrict__ yR,            // [B*T][256] bf16 (seq mode) or null
    const u16*  __restrict__ projL,  // [B*T][1024] bf16
    const float* __restrict__ WhhL,  // [1024][256]
    const float* __restrict__ bihL, const float* __restrict__ bhhL,
    u16* __restrict__ yL,
    u16* __restrict__ hbuf,          // [2][64][256] bf16 LSTM h exchange
    int* __restrict__ flags,         // [4] arrive counters
    float* __restrict__ feat,        // [64][512] f32 (last mode) or null
    int lastMode)
{
  __shared__ u16 hlds[16*256];       // RNN h state (bf16, swizzled)
  const int tid = threadIdx.x;
  const int lane = tid & 63, w = tid >> 6;
  const int l15 = lane & 15, l4 = lane >> 4, l7 = lane & 7;
  const int bid = blockIdx.x;

  if (bid < 4){
    // =============== RNN ===============
    const int g = bid;
    const int cb = 32*w;             // wave's 32 output cols
    bf16x8 bhi[2][8], blo[2][8];     // Whh^T frags, hi/lo split (128 VGPR)
    #pragma unroll
    for (int nb=0;nb<2;++nb){
      const int col = cb + nb*16 + l15;
      #pragma unroll
      for (int kb=0;kb<8;++kb){
        const float* wp = WhhR + (long)col*256 + kb*32 + l4*8;
        #pragma unroll
        for (int j=0;j<8;++j){
          float wv = wp[j];
          u16 hi = f2bf(wv);
          bhi[nb][kb][j] = (short)hi;
          blo[nb][kb][j] = (short)f2bf(wv - bf2f(hi));
        }
      }
    }
    float bias[2];
    #pragma unroll
    for (int nb=0;nb<2;++nb){ int col = cb+nb*16+l15; bias[nb]=bihR[col]+bhhR[col]; }

    u16 pfr[8];                       // proj prefetch (bf16 raw)
    #pragma unroll
    for (int nb=0;nb<2;++nb)
      #pragma unroll
      for (int j=0;j<4;++j)
        pfr[nb*4+j] = projR[((long)(16*g + l4*4 + j)*T_ + 0)*256 + cb + nb*16 + l15];

    for (int t=0; t<T_; ++t){
      lgkm0_barrier();               // h_{t-1} writes visible
      f32x4 acc0 = {0.f,0.f,0.f,0.f}, acc1 = acc0;
      if (t > 0){
        bf16x8 a[8];
        #pragma unroll
        for (int kb=0;kb<8;++kb){
          int bo = (l15*512 + kb*64 + l4*16) ^ ((l15&7)<<4);
          a[kb] = *(const bf16x8*)((const char*)hlds + bo);
        }
        #pragma unroll
        for (int kb=0;kb<8;++kb){
          acc0 = MFMA(a[kb], bhi[0][kb], acc0);
          acc0 = MFMA(a[kb], blo[0][kb], acc0);
          acc1 = MFMA(a[kb], bhi[1][kb], acc1);
          acc1 = MFMA(a[kb], blo[1][kb], acc1);
        }
      }
      float hv[2][4];
      #pragma unroll
      for (int nb=0;nb<2;++nb)
        #pragma unroll
        for (int j=0;j<4;++j){
          float pre = (nb ? acc1[j] : acc0[j]) + bf2f(pfr[nb*4+j]) + bias[nb];
          hv[nb][j] = tanhq(pre);
        }
      int tn = (t+1 < T_) ? t+1 : t;  // prefetch next step (crosses raw barriers)
      #pragma unroll
      for (int nb=0;nb<2;++nb)
        #pragma unroll
        for (int j=0;j<4;++j)
          pfr[nb*4+j] = projR[((long)(16*g + l4*4 + j)*T_ + tn)*256 + cb + nb*16 + l15];
      lgkm0_barrier();               // everyone done reading h_{t-1}
      #pragma unroll
      for (int nb=0;nb<2;++nb)
        #pragma unroll
        for (int j=0;j<4;++j){
          int m = l4*4 + j, u = cb + nb*16 + l15;
          u16 hb = f2bf(hv[nb][j]);
          int bo = (m*512 + u*2) ^ ((m&7)<<4);
          *(u16*)((char*)hlds + bo) = hb;
          if (yR) yR[((long)(16*g+m)*T_ + t)*256 + u] = hb;
          if (lastMode && t == T_-1) feat[(16*g+m)*512 + u] = hv[nb][j];
        }
    }
  } else {
    // =============== LSTM ===============
    const int wg = bid - 4;
    const int bg = wg >> 2, hg = wg & 3;
    const int ub = 64*hg + 8*w;      // wave's 8 hidden units
    const int ugl = ub + l7;         // lane's unit
    // col c=l15 within tile nb: gate = nb*2 + (c>>3), unit = ub + (c&7)
    bf16x8 bhi[2][8], blo[2][8];
    float bias[2];
    #pragma unroll
    for (int nb=0;nb<2;++nb){
      const int gate = nb*2 + (l15>>3);
      const long wr = (long)(gate*256 + ub + l7);
      bias[nb] = bihL[wr] + bhhL[wr];
      #pragma unroll
      for (int kb=0;kb<8;++kb){
        const float* wp = WhhL + wr*256 + kb*32 + l4*8;
        #pragma unroll
        for (int j=0;j<8;++j){
          float wv = wp[j];
          u16 hi = f2bf(wv);
          bhi[nb][kb][j] = (short)hi;
          blo[nb][kb][j] = (short)f2bf(wv - bf2f(hi));
        }
      }
    }
    u16 pfr[8];
    #pragma unroll
    for (int nb=0;nb<2;++nb){
      const int gate = nb*2 + (l15>>3);
      #pragma unroll
      for (int j=0;j<4;++j)
        pfr[nb*4+j] = projL[((long)(16*bg + l4*4 + j)*T_ + 0)*1024 + gate*256 + ub + l7];
    }
    float c4[4] = {0.f,0.f,0.f,0.f};
    const bool lowHalf = ((lane & 8) == 0);

    for (int t=0; t<T_; ++t){
      const int par = t & 1, pn = par ^ 1;
      if (t > 0 && tid == 0){
        while (__hip_atomic_load(flags + bg, __ATOMIC_RELAXED, __HIP_MEMORY_SCOPE_AGENT) < 4*t)
          __builtin_amdgcn_s_sleep(1);
        __threadfence();             // acquire: invalidate L1/L2 before h reads
      }
      lgkm0_barrier();               // join after spin
      f32x4 acc0 = {0.f,0.f,0.f,0.f}, acc1 = acc0;
      if (t > 0){
        bf16x8 a[8];                 // A frags straight from L2-resident hbuf
        const u16* hb = hbuf + par*16384 + (16*bg + l15)*256;
        #pragma unroll
        for (int kb=0;kb<8;++kb) a[kb] = *(const bf16x8*)(hb + kb*32 + l4*8);
        #pragma unroll
        for (int kb=0;kb<8;++kb){
          acc0 = MFMA(a[kb], bhi[0][kb], acc0);
          acc0 = MFMA(a[kb], blo[0][kb], acc0);
          acc1 = MFMA(a[kb], bhi[1][kb], acc1);
          acc1 = MFMA(a[kb], blo[1][kb], acc1);
        }
      }
      #pragma unroll
      for (int j=0;j<4;++j){
        float s0 = acc0[j] + bf2f(pfr[j])   + bias[0];   // i or f pre-act
        float s1 = acc1[j] + bf2f(pfr[4+j]) + bias[1];   // g or o pre-act
        float g0 = sigm(s0);
        float g1 = lowHalf ? tanhq(s1) : sigm(s1);
        float p0 = __shfl_xor(g0, 8);
        float p1 = __shfl_xor(g1, 8);
        float iv = lowHalf ? g0 : p0;
        float fv = lowHalf ? p0 : g0;
        float gv = lowHalf ? g1 : p1;
        float ov = lowHalf ? p1 : g1;
        float cv = fv * c4[j] + iv * gv;
        c4[j] = cv;
        float hval = ov * tanhq(cv);
        int m = l4*4 + j;
        if (lowHalf){
          u16 hb2 = f2bf(hval);
          hbuf[pn*16384 + (16*bg+m)*256 + ugl] = hb2;
          if (yL) yL[((long)(16*bg+m)*T_ + t)*256 + ugl] = hb2;
          if (lastMode && t == T_-1) feat[(16*bg+m)*512 + 256 + ugl] = hval;
        }
      }
      int tn = (t+1 < T_) ? t+1 : t;
      #pragma unroll
      for (int nb=0;nb<2;++nb){
        const int gate = nb*2 + (l15>>3);
        #pragma unroll
        for (int j=0;j<4;++j)
          pfr[nb*4+j] = projL[((long)(16*bg + l4*4 + j)*T_ + tn)*1024 + gate*256 + ub + l7];
      }
      // drain stores but keep the 8 prefetch loads in flight (counted vmcnt)
      asm volatile("s_waitcnt vmcnt(8)" ::: "memory");
      __builtin_amdgcn_s_barrier();
      asm volatile("" ::: "memory");
      if (tid == 0){ __threadfence(); atomicAdd(flags + bg, 1); }
    }
  }
}

// ---------------- FC: out[64,128] = feat[64,512] @ fcW[128,512]^T + b ----------------
__global__ void k_fc(const float* __restrict__ feat, const float* __restrict__ W,
                     const float* __restrict__ bias, float* __restrict__ out){
  int o = blockIdx.x*blockDim.x + threadIdx.x;
  if (o >= 64*128) return;
  int b = o >> 7, c = o & 127;
  float s = bias[c];
  const float* f  = feat + b*512;
  const float* wr = W + c*512;
  #pragma unroll 8
  for (int k=0;k<512;++k) s += f[k]*wr[k];
  out[o] = s;
}

extern "C" void kernel_launch(void* const* d_in, const int* in_sizes, int n_in,
                              void* d_out, int out_size, void* d_ws, size_t ws_size,
                              hipStream_t stream)
{
  (void)in_sizes; (void)n_in; (void)out_size; (void)ws_size;
  const float* rnn_x    = (const float*)d_in[0];
  const float* lstm_x   = (const float*)d_in[1];
  const float* rnn_Wih  = (const float*)d_in[2];
  const float* rnn_Whh  = (const float*)d_in[3];
  const float* rnn_bih  = (const float*)d_in[4];
  const float* rnn_bhh  = (const float*)d_in[5];
  const float* lstm_Wih = (const float*)d_in[6];
  const float* lstm_Whh = (const float*)d_in[7];
  const float* lstm_bih = (const float*)d_in[8];
  const float* lstm_bhh = (const float*)d_in[9];
  const float* fc_W     = (const float*)d_in[10];
  const float* fc_b     = (const float*)d_in[11];
  float* out = (float*)d_out;

  char* ws = (char*)d_ws; size_t off = 0;
  auto alloc = [&](size_t b)->char*{ char* p = ws + off; off += (b + 255) & ~(size_t)255; return p; };
  const size_t NE = (size_t)64*1024*256;          // B*T*H elems
  u16*  wih_r = (u16*)alloc(2*256*256*2);
  u16*  wih_l = (u16*)alloc(2*1024*256*2);
  u16*  xr    = (u16*)alloc(NE*2);                // rnn_x bf16, later y1R
  u16*  xl    = (u16*)alloc(NE*2);                // lstm_x bf16, later y1L
  u16*  projR = (u16*)alloc(NE*2);                // [65536][256]
  u16*  projL = (u16*)alloc(NE*4*2);              // [65536][1024]
  u16*  hbuf  = (u16*)alloc(2*64*256*2);
  int*  flags = (int*)alloc(256);
  float* feat = (float*)alloc(64*512*4);

  hipMemsetAsync(flags, 0, 256, stream);
  // f32 -> bf16
  k_cvt<<<2048,256,0,stream>>>(rnn_x,  xr, (int)(NE/4));
  k_cvt<<<2048,256,0,stream>>>(lstm_x, xl, (int)(NE/4));
  k_cvt<<<64, 256,0,stream>>>(rnn_Wih,  wih_r, 2*256*256/4);
  k_cvt<<<256,256,0,stream>>>(lstm_Wih, wih_l, 2*1024*256/4);
  // layer-1 projections
  k_gemm<<<dim3(512,2),256,0,stream>>>(xr, wih_r, projR, 256);
  k_gemm<<<dim3(512,8),256,0,stream>>>(xl, wih_l, projL, 1024);
  // layer-1 recurrences (RNN + LSTM concurrently); y written into xr/xl (inputs dead)
  k_rec<<<20,512,0,stream>>>(projR, rnn_Whh, rnn_bih, rnn_bhh, xr,
                             projL, lstm_Whh, lstm_bih, lstm_bhh, xl,
                             hbuf, flags, nullptr, 0);
  // layer-2 projections
  k_gemm<<<dim3(512,2),256,0,stream>>>(xr, wih_r + 256*256,  projR, 256);
  k_gemm<<<dim3(512,8),256,0,stream>>>(xl, wih_l + 1024*256, projL, 1024);
  // layer-2 recurrences -> feat (last step only)
  k_rec<<<20,512,0,stream>>>(projR, rnn_Whh + 256*256, rnn_bih + 256, rnn_bhh + 256, nullptr,
                             projL, lstm_Whh + 1024*256, lstm_bih + 1024, lstm_bhh + 1024, nullptr,
                             hbuf, flags + 32, feat, 1);
  // FC
  k_fc<<<32,256,0,stream>>>(feat, fc_W, fc_b, out);
}